// Round 1
// baseline (342.453 us; speedup 1.0000x reference)
//
#include <hip/hip_runtime.h>
#include <math.h>

#define NN 1024
#define DIN 128
#define PP 64
#define EE 32
#define HH 160

typedef __bf16 bf16x8 __attribute__((ext_vector_type(8)));
typedef float f32x4 __attribute__((ext_vector_type(4)));

__device__ __forceinline__ float wave_sum(float v) {
#pragma unroll
  for (int o = 32; o > 0; o >>= 1) v += __shfl_xor(v, o);
  return v;
}
__device__ __forceinline__ float wave_max(float v) {
#pragma unroll
  for (int o = 32; o > 0; o >>= 1) v = fmaxf(v, __shfl_xor(v, o));
  return v;
}

// Kernel 1: h = LN(x)@W1 + b1 ; hi = h@Wi ; hjb = h@Wj + ba1
__global__ __launch_bounds__(256) void precompute_kernel(
    const float* __restrict__ x,
    const float* __restrict__ g1, const float* __restrict__ b1ln,
    const float* __restrict__ W1, const float* __restrict__ b1,
    const float* __restrict__ Wa1, const float* __restrict__ ba1,
    float* __restrict__ h_out, float* __restrict__ hi_out,
    float* __restrict__ hjb_out)
{
  __shared__ float xraw[DIN];
  __shared__ float xn[DIN];
  __shared__ float hrow[PP];
  __shared__ float red[2];
  const int i = blockIdx.x;
  const int t = threadIdx.x;

  if (t < DIN) xraw[t] = x[(size_t)i * DIN + t];
  __syncthreads();
  if (t < 64) {
    float a = xraw[t], b = xraw[t + 64];
    float s  = wave_sum(a + b);
    float sq = wave_sum(a * a + b * b);
    if (t == 0) {
      float m = s * (1.f / DIN);
      float v = sq * (1.f / DIN) - m * m;
      red[0] = m;
      red[1] = rsqrtf(v + 1e-5f);
    }
  }
  __syncthreads();
  if (t < DIN) xn[t] = (xraw[t] - red[0]) * red[1] * g1[t] + b1ln[t];
  __syncthreads();
  if (t < PP) {
    float acc = b1[t];
#pragma unroll 8
    for (int k = 0; k < DIN; ++k) acc += xn[k] * W1[(size_t)k * PP + t];
    hrow[t] = acc;
    h_out[(size_t)i * PP + t] = acc;
  }
  __syncthreads();
  if (t < HH) {
    float a1 = 0.f, a2 = ba1[t];
#pragma unroll 8
    for (int p = 0; p < PP; ++p) {
      float hv = hrow[p];
      a1 += hv * Wa1[(size_t)p * HH + t];
      a2 += hv * Wa1[(size_t)(PP + p) * HH + t];
    }
    hi_out[(size_t)i * HH + t] = a1;
    hjb_out[(size_t)i * HH + t] = a2;
  }
}

// Kernel 2: per row i -- scores via MFMA einsum + GELU + Wa2 dot, softmax,
// att@h, LN2.
__global__ __launch_bounds__(256) void gat_main_kernel(
    const float* __restrict__ edge, const float* __restrict__ adj,
    const float* __restrict__ Wa1, const float* __restrict__ Wa2,
    const float* __restrict__ ba2, const float* __restrict__ g2,
    const float* __restrict__ b2, const float* __restrict__ h,
    const float* __restrict__ hi, const float* __restrict__ hjb,
    float* __restrict__ out)
{
  const int i = blockIdx.x;
  const int t = threadIdx.x;
  const int wave = t >> 6;
  const int lane = t & 63;
  const int c  = lane & 15;   // col within 16x16 tile
  const int rg = lane >> 4;   // row group 0..3

  __shared__ float srow[NN];
  __shared__ float hi_s[HH];
  __shared__ float red_s[8];
  __shared__ float obuf[4][PP];

  if (t < HH) hi_s[t] = hi[(size_t)i * HH + t];

  // B fragments: We[k][h] = Wa1[(128+k)*160 + h], k = rg*8+e, h = f*16+c
  bf16x8 bfrag[10];
  float wa2v[10];
#pragma unroll
  for (int f = 0; f < 10; ++f) {
    bf16x8 v;
#pragma unroll
    for (int e = 0; e < 8; ++e)
      v[e] = (__bf16)Wa1[(size_t)(2 * PP + rg * 8 + e) * HH + f * 16 + c];
    bfrag[f] = v;
    wa2v[f] = Wa2[f * 16 + c];
  }
  const float ba2v = ba2[0];
  __syncthreads();

  for (int it = 0; it < 16; ++it) {
    const int j0 = it * 64 + wave * 16;
    // A fragment: edge[i, j0+c, rg*8 + 0..7]  (8 contiguous floats, 32B aligned)
    const float* ep = edge + ((size_t)i * NN + (j0 + c)) * EE + rg * 8;
    float4 e0 = *(const float4*)ep;
    float4 e1 = *(const float4*)(ep + 4);
    bf16x8 afrag;
    afrag[0] = (__bf16)e0.x; afrag[1] = (__bf16)e0.y;
    afrag[2] = (__bf16)e0.z; afrag[3] = (__bf16)e0.w;
    afrag[4] = (__bf16)e1.x; afrag[5] = (__bf16)e1.y;
    afrag[6] = (__bf16)e1.z; afrag[7] = (__bf16)e1.w;

    float sc0 = 0.f, sc1 = 0.f, sc2 = 0.f, sc3 = 0.f;
#pragma unroll
    for (int f = 0; f < 10; ++f) {
      f32x4 acc = {0.f, 0.f, 0.f, 0.f};
      acc = __builtin_amdgcn_mfma_f32_16x16x32_bf16(afrag, bfrag[f], acc, 0, 0, 0);
      const int hcol = f * 16 + c;
      const float hiv = hi_s[hcol];
      const float w2 = wa2v[f];
#pragma unroll
      for (int r = 0; r < 4; ++r) {
        const int j = j0 + rg * 4 + r;
        float xv = acc[r] + hiv + hjb[(size_t)j * HH + hcol];
        float gl = 0.5f * xv * (1.f + erff(xv * 0.70710678118f));
        float term = gl * w2;
        if (r == 0) sc0 += term;
        else if (r == 1) sc1 += term;
        else if (r == 2) sc2 += term;
        else sc3 += term;
      }
    }
    float sc[4] = {sc0, sc1, sc2, sc3};
#pragma unroll
    for (int r = 0; r < 4; ++r) {
      float v = sc[r];
      v += __shfl_xor(v, 1);
      v += __shfl_xor(v, 2);
      v += __shfl_xor(v, 4);
      v += __shfl_xor(v, 8);
      sc[r] = v;
    }
    if (c == 0) {
#pragma unroll
      for (int r = 0; r < 4; ++r) {
        const int j = j0 + rg * 4 + r;
        float s = sc[r] + ba2v;
        s = (s >= 0.f) ? s : 0.2f * s;
        float a = adj[(size_t)i * NN + j] + ((i == j) ? 1.f : 0.f);
        srow[j] = (a > 0.f) ? s : -1e12f;
      }
    }
  }
  __syncthreads();

  // softmax over srow
  float mx = -INFINITY;
  for (int j = t; j < NN; j += 256) mx = fmaxf(mx, srow[j]);
  mx = wave_max(mx);
  if (lane == 0) red_s[wave] = mx;
  __syncthreads();
  mx = fmaxf(fmaxf(red_s[0], red_s[1]), fmaxf(red_s[2], red_s[3]));
  float ps = 0.f;
  for (int j = t; j < NN; j += 256) {
    float e_ = __expf(srow[j] - mx);
    srow[j] = e_;
    ps += e_;
  }
  ps = wave_sum(ps);
  if (lane == 0) red_s[4 + wave] = ps;
  __syncthreads();
  const float inv = 1.f / (red_s[4] + red_s[5] + red_s[6] + red_s[7]);
  __syncthreads();

  // out_row = att @ h  (partials per wave over j-ranges of 256)
  {
    const int p = t & 63;
    const int g = t >> 6;
    float acc = 0.f;
    const float* hp = h + (size_t)(g * 256) * PP + p;
#pragma unroll 4
    for (int j = 0; j < 256; ++j) acc += srow[g * 256 + j] * hp[(size_t)j * PP];
    obuf[g][p] = acc;
  }
  __syncthreads();
  if (t < PP) {
    float v = (obuf[0][t] + obuf[1][t] + obuf[2][t] + obuf[3][t]) * inv;
    float s = wave_sum(v);
    float mean = s * (1.f / PP);
    float d = v - mean;
    float var = wave_sum(d * d) * (1.f / PP);
    out[(size_t)i * PP + t] = d * rsqrtf(var + 1e-5f) * g2[t] + b2[t];
  }
}

extern "C" void kernel_launch(void* const* d_in, const int* in_sizes, int n_in,
                              void* d_out, int out_size, void* d_ws, size_t ws_size,
                              hipStream_t stream) {
  const float* node_features = (const float*)d_in[0];
  const float* edge_features = (const float*)d_in[1];
  const float* node_adjacent = (const float*)d_in[2];
  const float* ln1_g = (const float*)d_in[3];
  const float* ln1_b = (const float*)d_in[4];
  const float* W1    = (const float*)d_in[5];
  const float* b1    = (const float*)d_in[6];
  const float* Wa1   = (const float*)d_in[7];
  const float* ba1   = (const float*)d_in[8];
  const float* Wa2   = (const float*)d_in[9];
  const float* ba2   = (const float*)d_in[10];
  const float* ln2_g = (const float*)d_in[11];
  const float* ln2_b = (const float*)d_in[12];
  float* out = (float*)d_out;

  float* ws = (float*)d_ws;
  float* h_ws   = ws;                       // 1024*64
  float* hi_ws  = ws + NN * PP;             // 1024*160
  float* hjb_ws = ws + NN * PP + NN * HH;   // 1024*160

  precompute_kernel<<<NN, 256, 0, stream>>>(node_features, ln1_g, ln1_b, W1, b1,
                                            Wa1, ba1, h_ws, hi_ws, hjb_ws);
  gat_main_kernel<<<NN, 256, 0, stream>>>(edge_features, node_adjacent, Wa1,
                                          Wa2, ba2, ln2_g, ln2_b, h_ws, hi_ws,
                                          hjb_ws, out);
}

// Round 2
// 157.418 us; speedup vs baseline: 2.1754x; 2.1754x over previous
//
#include <hip/hip_runtime.h>
#include <math.h>

#define NN 1024
#define DIN 128
#define PP 64
#define EE 32
#define HH 160

typedef __bf16 bf16x8 __attribute__((ext_vector_type(8)));
typedef float f32x4 __attribute__((ext_vector_type(4)));

__device__ __forceinline__ float wave_sum(float v) {
#pragma unroll
  for (int o = 32; o > 0; o >>= 1) v += __shfl_xor(v, o);
  return v;
}
__device__ __forceinline__ float wave_max(float v) {
#pragma unroll
  for (int o = 32; o > 0; o >>= 1) v = fmaxf(v, __shfl_xor(v, o));
  return v;
}

// tanh-form GELU: x * sigmoid(1.5957691*(x + 0.044715 x^3)); err ~1e-4
__device__ __forceinline__ float fast_gelu(float x) {
  float u = 1.5957691216f * fmaf(0.044715f * x, x * x, x);
  float e = __expf(-u);
  return x / (1.f + e);
}

// Kernel 1: h = LN(x)@W1 + b1 (fp32 + bf16); hib = h@Wi + ba1
__global__ __launch_bounds__(256) void precompute_kernel(
    const float* __restrict__ x,
    const float* __restrict__ g1, const float* __restrict__ b1ln,
    const float* __restrict__ W1, const float* __restrict__ b1,
    const float* __restrict__ Wa1, const float* __restrict__ ba1,
    float* __restrict__ h_out, __bf16* __restrict__ hbf_out,
    float* __restrict__ hib_out)
{
  __shared__ float xraw[DIN];
  __shared__ float xn[DIN];
  __shared__ float hrow[PP];
  __shared__ float red[2];
  const int i = blockIdx.x;
  const int t = threadIdx.x;

  if (t < DIN) xraw[t] = x[(size_t)i * DIN + t];
  __syncthreads();
  if (t < 64) {
    float a = xraw[t], b = xraw[t + 64];
    float s  = wave_sum(a + b);
    float sq = wave_sum(a * a + b * b);
    if (t == 0) {
      float m = s * (1.f / DIN);
      float v = sq * (1.f / DIN) - m * m;
      red[0] = m;
      red[1] = rsqrtf(v + 1e-5f);
    }
  }
  __syncthreads();
  if (t < DIN) xn[t] = (xraw[t] - red[0]) * red[1] * g1[t] + b1ln[t];
  __syncthreads();
  if (t < PP) {
    float acc = b1[t];
#pragma unroll 8
    for (int k = 0; k < DIN; ++k) acc += xn[k] * W1[(size_t)k * PP + t];
    hrow[t] = acc;
    h_out[(size_t)i * PP + t] = acc;
    hbf_out[(size_t)i * PP + t] = (__bf16)acc;
  }
  __syncthreads();
  if (t < HH) {
    float a1 = ba1[t];
#pragma unroll 8
    for (int p = 0; p < PP; ++p) a1 += hrow[p] * Wa1[(size_t)p * HH + t];
    hib_out[(size_t)i * HH + t] = a1;
  }
}

// Pack B = [We(32x160); Wj(64x160)] into MFMA-fragment order, bf16.
// idx = (((f*3+chunk)*4+rg)*16+c)*8+e  ->  W[k=chunk*32+rg*8+e][f*16+c]
__global__ __launch_bounds__(256) void pack_kernel(
    const float* __restrict__ Wa1, __bf16* __restrict__ Bpack)
{
  const int t = threadIdx.x;
  for (int idx = t; idx < 15360; idx += 256) {
    int e  = idx & 7;
    int c  = (idx >> 3) & 15;
    int rg = (idx >> 7) & 3;
    int fc = idx >> 9;          // f*3+chunk
    int f = fc / 3, chunk = fc - 3 * f;
    int k = chunk * 32 + rg * 8 + e;
    int grow = (k < 32) ? (2 * PP + k) : (PP + (k - 32));
    Bpack[idx] = (__bf16)Wa1[(size_t)grow * HH + f * 16 + c];
  }
}

// Kernel 2: per row i -- K=96 MFMA (edge@We + h_j@Wj), fast GELU, Wa2 dot,
// leaky-relu+mask, softmax, att@h, LN2.
__global__ __launch_bounds__(256) void gat_main_kernel(
    const float* __restrict__ edge, const float* __restrict__ adj,
    const __bf16* __restrict__ Bpack_g, const float* __restrict__ Wa2,
    const float* __restrict__ ba2, const float* __restrict__ g2,
    const float* __restrict__ b2, const float* __restrict__ h,
    const float* __restrict__ hib, const __bf16* __restrict__ hbf,
    float* __restrict__ out)
{
  const int i = blockIdx.x;
  const int t = threadIdx.x;
  const int wave = t >> 6;
  const int lane = t & 63;
  const int c  = lane & 15;
  const int rg = lane >> 4;

  __shared__ float4 BpV[1920];           // 30720 B packed B operand
  __shared__ float srow[NN];
  __shared__ float hib_s[HH];
  __shared__ float red_s[8];
  __shared__ float obuf[4][PP];
  const __bf16* Bp = (const __bf16*)BpV;

  {
    const float4* src = (const float4*)Bpack_g;
    for (int idx = t; idx < 1920; idx += 256) BpV[idx] = src[idx];
  }
  if (t < HH) hib_s[t] = hib[(size_t)i * HH + t];
  float wa2v[10];
#pragma unroll
  for (int f = 0; f < 10; ++f) wa2v[f] = Wa2[f * 16 + c];
  const float ba2v = ba2[0];
  __syncthreads();

  // prologue: load it=0 fragments
  const int jl = wave * 16 + c;
  const float* eptr = edge + ((size_t)i * NN + jl) * EE + rg * 8;
  const __bf16* hptr = hbf + (size_t)jl * PP + rg * 8;
  float4 ea = *(const float4*)eptr;
  float4 eb = *(const float4*)(eptr + 4);
  bf16x8 ha = *(const bf16x8*)hptr;
  bf16x8 hb = *(const bf16x8*)(hptr + 32);

  for (int it = 0; it < 16; ++it) {
    const int j0 = it * 64 + wave * 16;
    bf16x8 a0;
    a0[0] = (__bf16)ea.x; a0[1] = (__bf16)ea.y;
    a0[2] = (__bf16)ea.z; a0[3] = (__bf16)ea.w;
    a0[4] = (__bf16)eb.x; a0[5] = (__bf16)eb.y;
    a0[6] = (__bf16)eb.z; a0[7] = (__bf16)eb.w;
    const bf16x8 a1 = ha;
    const bf16x8 a2 = hb;
    // prefetch next tile (hidden under the f-loop)
    if (it < 15) {
      eptr += 64 * EE;
      hptr += 64 * PP;
      ea = *(const float4*)eptr;
      eb = *(const float4*)(eptr + 4);
      ha = *(const bf16x8*)hptr;
      hb = *(const bf16x8*)(hptr + 32);
    }

    float sc0 = 0.f, sc1 = 0.f, sc2 = 0.f, sc3 = 0.f;
#pragma unroll
    for (int f = 0; f < 10; ++f) {
      const __bf16* bbase = Bp + f * 1536 + rg * 128 + c * 8;
      bf16x8 b0  = *(const bf16x8*)(bbase);
      bf16x8 b1  = *(const bf16x8*)(bbase + 512);
      bf16x8 b2v = *(const bf16x8*)(bbase + 1024);
      f32x4 acc = {0.f, 0.f, 0.f, 0.f};
      acc = __builtin_amdgcn_mfma_f32_16x16x32_bf16(a0, b0,  acc, 0, 0, 0);
      acc = __builtin_amdgcn_mfma_f32_16x16x32_bf16(a1, b1,  acc, 0, 0, 0);
      acc = __builtin_amdgcn_mfma_f32_16x16x32_bf16(a2, b2v, acc, 0, 0, 0);
      const float base = hib_s[f * 16 + c];
      const float w2 = wa2v[f];
      sc0 += w2 * fast_gelu(acc[0] + base);
      sc1 += w2 * fast_gelu(acc[1] + base);
      sc2 += w2 * fast_gelu(acc[2] + base);
      sc3 += w2 * fast_gelu(acc[3] + base);
    }
    float sc[4] = {sc0, sc1, sc2, sc3};
#pragma unroll
    for (int r = 0; r < 4; ++r) {
      float v = sc[r];
      v += __shfl_xor(v, 1);
      v += __shfl_xor(v, 2);
      v += __shfl_xor(v, 4);
      v += __shfl_xor(v, 8);
      sc[r] = v;
    }
    if (c == 0) {
#pragma unroll
      for (int r = 0; r < 4; ++r) {
        const int j = j0 + rg * 4 + r;
        float s = sc[r] + ba2v;
        s = (s >= 0.f) ? s : 0.2f * s;
        float a = adj[(size_t)i * NN + j] + ((i == j) ? 1.f : 0.f);
        srow[j] = (a > 0.f) ? s : -1e12f;
      }
    }
  }
  __syncthreads();

  // softmax over srow
  float mx = -INFINITY;
  for (int j = t; j < NN; j += 256) mx = fmaxf(mx, srow[j]);
  mx = wave_max(mx);
  if (lane == 0) red_s[wave] = mx;
  __syncthreads();
  mx = fmaxf(fmaxf(red_s[0], red_s[1]), fmaxf(red_s[2], red_s[3]));
  float ps = 0.f;
  for (int j = t; j < NN; j += 256) {
    float e_ = __expf(srow[j] - mx);
    srow[j] = e_;
    ps += e_;
  }
  ps = wave_sum(ps);
  if (lane == 0) red_s[4 + wave] = ps;
  __syncthreads();
  const float inv = 1.f / (red_s[4] + red_s[5] + red_s[6] + red_s[7]);
  __syncthreads();

  // out_row = att @ h
  {
    const int p = t & 63;
    const int g = t >> 6;
    float acc = 0.f;
    const float* hp = h + (size_t)(g * 256) * PP + p;
#pragma unroll 4
    for (int j = 0; j < 256; ++j) acc += srow[g * 256 + j] * hp[(size_t)j * PP];
    obuf[g][p] = acc;
  }
  __syncthreads();
  if (t < PP) {
    float v = (obuf[0][t] + obuf[1][t] + obuf[2][t] + obuf[3][t]) * inv;
    float s = wave_sum(v);
    float mean = s * (1.f / PP);
    float d = v - mean;
    float var = wave_sum(d * d) * (1.f / PP);
    out[(size_t)i * PP + t] = d * rsqrtf(var + 1e-5f) * g2[t] + b2[t];
  }
}

extern "C" void kernel_launch(void* const* d_in, const int* in_sizes, int n_in,
                              void* d_out, int out_size, void* d_ws, size_t ws_size,
                              hipStream_t stream) {
  const float* node_features = (const float*)d_in[0];
  const float* edge_features = (const float*)d_in[1];
  const float* node_adjacent = (const float*)d_in[2];
  const float* ln1_g = (const float*)d_in[3];
  const float* ln1_b = (const float*)d_in[4];
  const float* W1    = (const float*)d_in[5];
  const float* b1    = (const float*)d_in[6];
  const float* Wa1   = (const float*)d_in[7];
  const float* ba1   = (const float*)d_in[8];
  const float* Wa2   = (const float*)d_in[9];
  const float* ba2   = (const float*)d_in[10];
  const float* ln2_g = (const float*)d_in[11];
  const float* ln2_b = (const float*)d_in[12];
  float* out = (float*)d_out;

  float* ws = (float*)d_ws;
  float*  h_ws    = ws;                                   // 65536 f32
  float*  hib_ws  = ws + NN * PP;                         // 163840 f32
  __bf16* Bpack_ws = (__bf16*)(ws + NN * PP + NN * HH);   // 15360 bf16
  __bf16* hbf_ws   = Bpack_ws + 15360;                    // 65536 bf16

  precompute_kernel<<<NN, 256, 0, stream>>>(node_features, ln1_g, ln1_b, W1, b1,
                                            Wa1, ba1, h_ws, hbf_ws, hib_ws);
  pack_kernel<<<1, 256, 0, stream>>>(Wa1, Bpack_ws);
  gat_main_kernel<<<NN, 256, 0, stream>>>(edge_features, node_adjacent,
                                          Bpack_ws, Wa2, ba2, ln2_g, ln2_b,
                                          h_ws, hib_ws, hbf_ws, out);
}

// Round 3
// 135.174 us; speedup vs baseline: 2.5334x; 1.1646x over previous
//
#include <hip/hip_runtime.h>
#include <math.h>

#define NN 1024
#define DIN 128
#define PP 64
#define EE 32
#define HH 160

typedef __bf16 bf16x8 __attribute__((ext_vector_type(8)));
typedef float f32x4 __attribute__((ext_vector_type(4)));

__device__ __forceinline__ float wave_sum(float v) {
#pragma unroll
  for (int o = 32; o > 0; o >>= 1) v += __shfl_xor(v, o);
  return v;
}
__device__ __forceinline__ float wave_max(float v) {
#pragma unroll
  for (int o = 32; o > 0; o >>= 1) v = fmaxf(v, __shfl_xor(v, o));
  return v;
}

// tanh-form GELU, fast div: err ~3e-4 absolute
__device__ __forceinline__ float fast_gelu(float x) {
  float u = fmaf(x, 0.044715f * x * x, x);
  float e = __expf(-1.5957691216f * u);
  return __fdividef(x, 1.f + e);
}

// Kernel 1: h = LN(x)@W1 + b1 (fp32 + bf16); hib = h@Wi + ba1
__global__ __launch_bounds__(256) void precompute_kernel(
    const float* __restrict__ x,
    const float* __restrict__ g1, const float* __restrict__ b1ln,
    const float* __restrict__ W1, const float* __restrict__ b1,
    const float* __restrict__ Wa1, const float* __restrict__ ba1,
    float* __restrict__ h_out, __bf16* __restrict__ hbf_out,
    float* __restrict__ hib_out)
{
  __shared__ float xraw[DIN];
  __shared__ float xn[DIN];
  __shared__ float hrow[PP];
  __shared__ float red[2];
  const int i = blockIdx.x;
  const int t = threadIdx.x;

  if (t < DIN) xraw[t] = x[(size_t)i * DIN + t];
  __syncthreads();
  if (t < 64) {
    float a = xraw[t], b = xraw[t + 64];
    float s  = wave_sum(a + b);
    float sq = wave_sum(a * a + b * b);
    if (t == 0) {
      float m = s * (1.f / DIN);
      float v = sq * (1.f / DIN) - m * m;
      red[0] = m;
      red[1] = rsqrtf(v + 1e-5f);
    }
  }
  __syncthreads();
  if (t < DIN) xn[t] = (xraw[t] - red[0]) * red[1] * g1[t] + b1ln[t];
  __syncthreads();
  if (t < PP) {
    float acc = b1[t];
#pragma unroll 8
    for (int k = 0; k < DIN; ++k) acc += xn[k] * W1[(size_t)k * PP + t];
    hrow[t] = acc;
    h_out[(size_t)i * PP + t] = acc;
    hbf_out[(size_t)i * PP + t] = (__bf16)acc;
  }
  __syncthreads();
  if (t < HH) {
    float a1 = ba1[t];
#pragma unroll 8
    for (int p = 0; p < PP; ++p) a1 += hrow[p] * Wa1[(size_t)p * HH + t];
    hib_out[(size_t)i * HH + t] = a1;
  }
}

// Pack B = [We(32x160); Wj(64x160)] into MFMA-fragment order, bf16.
__global__ __launch_bounds__(256) void pack_kernel(
    const float* __restrict__ Wa1, __bf16* __restrict__ Bpack)
{
  const int t = threadIdx.x;
  for (int idx = t; idx < 15360; idx += 256) {
    int e  = idx & 7;
    int c  = (idx >> 3) & 15;
    int rg = (idx >> 7) & 3;
    int fc = idx >> 9;          // f*3+chunk
    int f = fc / 3, chunk = fc - 3 * f;
    int k = chunk * 32 + rg * 8 + e;
    int grow = (k < 32) ? (2 * PP + k) : (PP + (k - 32));
    Bpack[idx] = (__bf16)Wa1[(size_t)grow * HH + f * 16 + c];
  }
}

// Per-row compaction: jidx[i][*] = ascending j where adj[i][j]>0 or j==i.
__global__ __launch_bounds__(256) void compact_kernel(
    const float* __restrict__ adj, unsigned short* __restrict__ jidx,
    int* __restrict__ cnt)
{
  const int i = blockIdx.x;
  const int t = threadIdx.x;
  const int wv = t >> 6, lane = t & 63;
  __shared__ int wt[4];
  unsigned long long m[4];
  int tot = 0;
#pragma unroll
  for (int r = 0; r < 4; ++r) {
    int j = wv * 256 + r * 64 + lane;
    bool flag = (adj[(size_t)i * NN + j] > 0.f) || (j == i);
    m[r] = __ballot(flag);
    tot += (int)__popcll(m[r]);
  }
  if (lane == 0) wt[wv] = tot;
  __syncthreads();
  int off = 0;
  for (int w = 0; w < wv; ++w) off += wt[w];
  const unsigned long long lt = (1ull << lane) - 1ull;
#pragma unroll
  for (int r = 0; r < 4; ++r) {
    if ((m[r] >> lane) & 1ull) {
      int pos = off + (int)__popcll(m[r] & lt);
      jidx[(size_t)i * NN + pos] = (unsigned short)(wv * 256 + r * 64 + lane);
    }
    off += (int)__popcll(m[r]);
  }
  if (t == 0) cnt[i] = wt[0] + wt[1] + wt[2] + wt[3];
}

// Kernel 2: per row i over COMPACTED j -- K=96 MFMA, fast GELU, Wa2 dot,
// leaky-relu, softmax, att@h, LN2.
__global__ __launch_bounds__(256) void gat_main_kernel(
    const float* __restrict__ edge,
    const __bf16* __restrict__ Bpack_g, const float* __restrict__ Wa2,
    const float* __restrict__ ba2, const float* __restrict__ g2,
    const float* __restrict__ b2, const float* __restrict__ h,
    const float* __restrict__ hib, const __bf16* __restrict__ hbf,
    const unsigned short* __restrict__ jidx, const int* __restrict__ cnt_g,
    float* __restrict__ out)
{
  const int i = blockIdx.x;
  const int t = threadIdx.x;
  const int wave = t >> 6;
  const int lane = t & 63;
  const int c  = lane & 15;
  const int rg = lane >> 4;

  __shared__ float4 BpV[1920];            // 30720 B packed B operand
  __shared__ float sc_s[NN];              // compacted scores
  __shared__ unsigned short jidx_s[NN];
  __shared__ float hib_s[HH];
  __shared__ float red_s[8];
  __shared__ float obuf[4][PP];
  const __bf16* Bp = (const __bf16*)BpV;

  {
    const float4* src = (const float4*)Bpack_g;
    for (int idx = t; idx < 1920; idx += 256) BpV[idx] = src[idx];
  }
  {
    const uint4* jsrc = (const uint4*)(jidx + (size_t)i * NN);
    uint4* jdst = (uint4*)jidx_s;
    if (t < 128) jdst[t] = jsrc[t];
  }
  if (t < HH) hib_s[t] = hib[(size_t)i * HH + t];
  float wa2v[10];
#pragma unroll
  for (int f = 0; f < 10; ++f) wa2v[f] = Wa2[f * 16 + c];
  const float ba2v = ba2[0];
  const int cnt = cnt_g[i];
  const int nt = (cnt + 63) >> 6;
  __syncthreads();

  // prologue: load tile 0 fragments
  int pc = wave * 16 + c;
  if (pc > cnt - 1) pc = cnt - 1;
  int jj = jidx_s[pc];
  const float* eb0 = edge + (size_t)i * NN * EE + rg * 8;
  float4 ea = *(const float4*)(eb0 + (size_t)jj * EE);
  float4 eb = *(const float4*)(eb0 + (size_t)jj * EE + 4);
  bf16x8 ha = *(const bf16x8*)(hbf + (size_t)jj * PP + rg * 8);
  bf16x8 hb = *(const bf16x8*)(hbf + (size_t)jj * PP + rg * 8 + 32);

  for (int it = 0; it < nt; ++it) {
    bf16x8 a0;
    a0[0] = (__bf16)ea.x; a0[1] = (__bf16)ea.y;
    a0[2] = (__bf16)ea.z; a0[3] = (__bf16)ea.w;
    a0[4] = (__bf16)eb.x; a0[5] = (__bf16)eb.y;
    a0[6] = (__bf16)eb.z; a0[7] = (__bf16)eb.w;
    const bf16x8 a1 = ha;
    const bf16x8 a2 = hb;
    // prefetch next tile (hidden under the f-loop)
    if (it + 1 < nt) {
      int pn = (it + 1) * 64 + wave * 16 + c;
      if (pn > cnt - 1) pn = cnt - 1;
      int j2 = jidx_s[pn];
      ea = *(const float4*)(eb0 + (size_t)j2 * EE);
      eb = *(const float4*)(eb0 + (size_t)j2 * EE + 4);
      ha = *(const bf16x8*)(hbf + (size_t)j2 * PP + rg * 8);
      hb = *(const bf16x8*)(hbf + (size_t)j2 * PP + rg * 8 + 32);
    }

    float sc0 = 0.f, sc1 = 0.f, sc2 = 0.f, sc3 = 0.f;
#pragma unroll
    for (int f = 0; f < 10; ++f) {
      const __bf16* bbase = Bp + f * 1536 + rg * 128 + c * 8;
      bf16x8 b0  = *(const bf16x8*)(bbase);
      bf16x8 b1  = *(const bf16x8*)(bbase + 512);
      bf16x8 b2v = *(const bf16x8*)(bbase + 1024);
      f32x4 acc = {0.f, 0.f, 0.f, 0.f};
      acc = __builtin_amdgcn_mfma_f32_16x16x32_bf16(a0, b0,  acc, 0, 0, 0);
      acc = __builtin_amdgcn_mfma_f32_16x16x32_bf16(a1, b1,  acc, 0, 0, 0);
      acc = __builtin_amdgcn_mfma_f32_16x16x32_bf16(a2, b2v, acc, 0, 0, 0);
      const float base = hib_s[f * 16 + c];
      const float w2 = wa2v[f];
      sc0 = fmaf(w2, fast_gelu(acc[0] + base), sc0);
      sc1 = fmaf(w2, fast_gelu(acc[1] + base), sc1);
      sc2 = fmaf(w2, fast_gelu(acc[2] + base), sc2);
      sc3 = fmaf(w2, fast_gelu(acc[3] + base), sc3);
    }
    float sc[4] = {sc0, sc1, sc2, sc3};
#pragma unroll
    for (int r = 0; r < 4; ++r) {
      float v = sc[r];
      v += __shfl_xor(v, 1);
      v += __shfl_xor(v, 2);
      v += __shfl_xor(v, 4);
      v += __shfl_xor(v, 8);
      sc[r] = v;
    }
    if (c == 0) {
#pragma unroll
      for (int r = 0; r < 4; ++r) {
        const int pos = it * 64 + wave * 16 + rg * 4 + r;
        if (pos < cnt) {
          float s = sc[r] + ba2v;
          sc_s[pos] = (s >= 0.f) ? s : 0.2f * s;
        }
      }
    }
  }
  __syncthreads();

  // softmax over sc_s[0..cnt)
  float mx = -INFINITY;
  for (int p_ = t; p_ < cnt; p_ += 256) mx = fmaxf(mx, sc_s[p_]);
  mx = wave_max(mx);
  if (lane == 0) red_s[wave] = mx;
  __syncthreads();
  mx = fmaxf(fmaxf(red_s[0], red_s[1]), fmaxf(red_s[2], red_s[3]));
  float ps = 0.f;
  for (int p_ = t; p_ < cnt; p_ += 256) {
    float e_ = __expf(sc_s[p_] - mx);
    sc_s[p_] = e_;
    ps += e_;
  }
  ps = wave_sum(ps);
  if (lane == 0) red_s[4 + wave] = ps;
  __syncthreads();
  const float inv = 1.f / (red_s[4] + red_s[5] + red_s[6] + red_s[7]);
  __syncthreads();

  // out_row = att @ h over compacted list
  {
    const int p = t & 63;
    const int g = t >> 6;
    float acc = 0.f;
    for (int pos = g; pos < cnt; pos += 4) {
      const int j = jidx_s[pos];
      acc = fmaf(sc_s[pos], h[(size_t)j * PP + p], acc);
    }
    obuf[g][p] = acc;
  }
  __syncthreads();
  if (t < PP) {
    float v = (obuf[0][t] + obuf[1][t] + obuf[2][t] + obuf[3][t]) * inv;
    float s = wave_sum(v);
    float mean = s * (1.f / PP);
    float d = v - mean;
    float var = wave_sum(d * d) * (1.f / PP);
    out[(size_t)i * PP + t] = d * rsqrtf(var + 1e-5f) * g2[t] + b2[t];
  }
}

extern "C" void kernel_launch(void* const* d_in, const int* in_sizes, int n_in,
                              void* d_out, int out_size, void* d_ws, size_t ws_size,
                              hipStream_t stream) {
  const float* node_features = (const float*)d_in[0];
  const float* edge_features = (const float*)d_in[1];
  const float* node_adjacent = (const float*)d_in[2];
  const float* ln1_g = (const float*)d_in[3];
  const float* ln1_b = (const float*)d_in[4];
  const float* W1    = (const float*)d_in[5];
  const float* b1    = (const float*)d_in[6];
  const float* Wa1   = (const float*)d_in[7];
  const float* ba1   = (const float*)d_in[8];
  const float* Wa2   = (const float*)d_in[9];
  const float* ba2   = (const float*)d_in[10];
  const float* ln2_g = (const float*)d_in[11];
  const float* ln2_b = (const float*)d_in[12];
  float* out = (float*)d_out;

  char* ws = (char*)d_ws;
  float*  h_ws     = (float*)(ws);                    // 262144 B
  float*  hib_ws   = (float*)(ws + 262144);           // 655360 B
  __bf16* Bpack_ws = (__bf16*)(ws + 917504);          // 30720 B
  __bf16* hbf_ws   = (__bf16*)(ws + 948224);          // 131072 B
  unsigned short* jidx_ws = (unsigned short*)(ws + 1079296); // 2097152 B
  int*    cnt_ws   = (int*)(ws + 3176448);            // 4096 B

  precompute_kernel<<<NN, 256, 0, stream>>>(node_features, ln1_g, ln1_b, W1, b1,
                                            Wa1, ba1, h_ws, hbf_ws, hib_ws);
  pack_kernel<<<1, 256, 0, stream>>>(Wa1, Bpack_ws);
  compact_kernel<<<NN, 256, 0, stream>>>(node_adjacent, jidx_ws, cnt_ws);
  gat_main_kernel<<<NN, 256, 0, stream>>>(edge_features, Bpack_ws, Wa2, ba2,
                                          ln2_g, ln2_b, h_ws, hib_ws, hbf_ws,
                                          jidx_ws, cnt_ws, out);
}